// Round 9
// baseline (213.671 us; speedup 1.0000x reference)
//
#include <hip/hip_runtime.h>
#include <hip/hip_bf16.h>
#include <math.h>

#define NN 10000
#define NE 131072

typedef __attribute__((ext_vector_type(8))) short short8;
typedef __attribute__((ext_vector_type(4))) float f32x4;

__device__ __forceinline__ float silu_f(float x) {
    return x / (1.0f + __expf(-x));
}

// round-to-nearest-even f32 -> bf16 (finite inputs only)
__device__ __forceinline__ unsigned short f2bf(float f) {
    unsigned int u = __float_as_uint(f);
    u += 0x7FFFu + ((u >> 16) & 1u);
    return (unsigned short)(u >> 16);
}

// packed pair via HW v_cvt_pk_bf16_f32 (x = low half)
__device__ __forceinline__ unsigned int pk_bf16(float lo, float hi) {
    __hip_bfloat162 h = __float22bfloat162_rn(float2{lo, hi});
    return *reinterpret_cast<unsigned int*>(&h);
}

// ---------------------------------------------------------------------------
// D1: prep (692 blocks).  hist already zeroed by D0 memset.  (R7-proven)
// ---------------------------------------------------------------------------
__global__ __launch_bounds__(256)
void prep_kernel(const int* __restrict__ A,
                 const int* __restrict__ edst,
                 const float* __restrict__ emb_tab,
                 const float* __restrict__ W1, const float* __restrict__ b1,
                 const float* __restrict__ W2, const float* __restrict__ b2,
                 const float* __restrict__ W3, const float* __restrict__ b3,
                 const float* __restrict__ fcW1,
                 const float* __restrict__ fcW2,
                 const float* __restrict__ fcW3,
                 const float* __restrict__ fcW4,
                 int* __restrict__ hist,
                 int* __restrict__ rank,
                 float* __restrict__ outg,
                 float* __restrict__ Ai,
                 unsigned short* __restrict__ Wg,
                 unsigned short* __restrict__ Bg)
{
    const int blk = blockIdx.x;
    const int tid = threadIdx.x;

    if (blk < 40) {
        // node MLP -> Ai
        int nd = blk * 256 + tid;
        if (nd >= NN) return;
        int a = A[nd];
        float h[16];
#pragma unroll
        for (int i = 0; i < 16; ++i) h[i] = emb_tab[a * 16 + i];
        float h1[64];
#pragma unroll
        for (int j = 0; j < 64; ++j) h1[j] = b1[j];
#pragma unroll
        for (int i = 0; i < 16; ++i) {
            float hv = h[i];
#pragma unroll
            for (int j = 0; j < 64; ++j) h1[j] += hv * W1[i * 64 + j];
        }
#pragma unroll
        for (int j = 0; j < 64; ++j) h1[j] = silu_f(h1[j]);
        float h2[32];
#pragma unroll
        for (int j = 0; j < 32; ++j) h2[j] = b2[j];
#pragma unroll
        for (int i = 0; i < 64; ++i) {
            float hv = h1[i];
#pragma unroll
            for (int j = 0; j < 32; ++j) h2[j] += hv * W2[i * 32 + j];
        }
#pragma unroll
        for (int j = 0; j < 32; ++j) h2[j] = silu_f(h2[j]);
#pragma unroll
        for (int j = 0; j < 8; ++j) {
            float s = b3[j];
#pragma unroll
            for (int i = 0; i < 32; ++i) s += h2[i] * W3[i * 8 + j];
            Ai[nd * 8 + j] = s;
        }
    } else if (blk < 80) {
        // prep_W: 20 frags of 512 bf16
        int i = (blk - 40) * 256 + tid;   // [0, 10240)
        int j    = i & 7;
        int lane = (i >> 3) & 63;
        int f    = i >> 9;
        int q = lane >> 4, n = lane & 15;
        int L, kf, nt;
        if (f < 4)       { L = 1; kf = 0;             nt = f; }
        else if (f < 12) { L = 2; kf = (f - 4) >> 2;  nt = (f - 4) & 3; }
        else             { L = 3; kf = (f - 12) >> 2; nt = (f - 12) & 3; }
        int k = kf * 32 + q * 8 + j;
        int col = nt * 16 + n;
        float v = 0.0f;
        if (L == 1)      { if (k < 10) v = fcW1[k * 64 + col]; }
        else if (L == 2) v = fcW2[k * 64 + col];
        else             v = fcW3[k * 64 + col];
        Wg[i] = f2bf(v);
    } else if (blk < 592) {
        // prep_B inverse-mapped + histogram/rank
        int linear = (blk - 80) * 256 + tid;   // [0, 131072)
        rank[linear] = atomicAdd(&hist[edst[linear]], 1);
        if (linear < 114688) {                 // 64 * 1792 real elements
            int k = linear / 1792;
            int t = linear - k * 1792;
            int uv, wc;
            if (t < 1024)      { uv = t >> 4;            wc = t & 15; }
            else if (t < 1536) { int r = t - 1024; uv = r >> 3; wc = 16 + (r & 7); }
            else               { int r = t - 1536; uv = r >> 2; wc = 24 + (r & 3); }
            int h  = uv >> 5;
            int q  = (uv >> 3) & 3;
            int j  = uv & 7;
            int nt = wc >> 4;
            int n  = wc & 15;
            int i  = (k << 11) | (h << 10) | (nt << 9) | (((q << 4) | n) << 3) | j;
            Bg[i] = f2bf(fcW4[linear]);
        } else {                               // zero padding: wc in [28,32)
            int z  = linear - 114688;          // [0, 16384)
            int k  = z >> 8;
            int r  = z & 255;
            int uv = r >> 2;
            int c2 = z & 3;
            int h  = uv >> 5;
            int q  = (uv >> 3) & 3;
            int j  = uv & 7;
            int i  = (k << 11) | (h << 10) | (1 << 9) | (((q << 4) | (12 + c2)) << 3) | j;
            Bg[i] = 0;
        }
    } else {
        // zero out
        int t = (blk - 592) * 256 + tid;
        float4 z = float4{0.f, 0.f, 0.f, 0.f};
        for (int r = t; r < 150000; r += 25600)
            ((float4*)outg)[r] = z;
    }
}

// ---------------------------------------------------------------------------
// D2: scan+scatter (512 blocks), atomic-free.  (R7-proven)
// ---------------------------------------------------------------------------
__global__ __launch_bounds__(256)
void scanrank_kernel(const int* __restrict__ edst,
                     const int* __restrict__ hist,
                     const int* __restrict__ rank,
                     int* __restrict__ sortidx)
{
    __shared__ int offs[NN];    // 40000 B
    __shared__ int part[256];
    const int tid = threadIdx.x;

    int loc[40];
    int s = 0;
    if (tid < 250) {
        const int4* h4 = (const int4*)(hist) + tid * 10;
#pragma unroll
        for (int v = 0; v < 10; ++v) {
            int4 x = h4[v];
            loc[v * 4 + 0] = x.x; loc[v * 4 + 1] = x.y;
            loc[v * 4 + 2] = x.z; loc[v * 4 + 3] = x.w;
            s += x.x + x.y + x.z + x.w;
        }
    } else {
#pragma unroll
        for (int r = 0; r < 40; ++r) loc[r] = 0;
    }
    part[tid] = s;
    __syncthreads();
#pragma unroll
    for (int off = 1; off < 256; off <<= 1) {
        int v = (tid >= off) ? part[tid - off] : 0;
        __syncthreads();
        part[tid] += v;
        __syncthreads();
    }
    if (tid < 250) {
        int run = part[tid] - s;
        int base = tid * 40;
#pragma unroll
        for (int r = 0; r < 40; ++r) { offs[base + r] = run; run += loc[r]; }
    }
    __syncthreads();

    int e = blockIdx.x * 256 + tid;
    int d = edst[e];
    sortidx[offs[d] + rank[e]] = e;
}

// ---------------------------------------------------------------------------
// D3: fused edge pipeline, 32 EDGES PER WAVE (grid 1024 -> 16 waves/CU,
// double the old occupancy which was capped by 2048 total waves).
// W/B fragments direct from global (L2-resident); all cross-lane state in
// registers + __shfl; LDS = per-wave act buffer only -> ZERO barriers.
// actw layout: pre-transpose [32 edges][72 (64 used)], post [64 k][36
// (32 used)] -- both 2304 ushorts; stride 72B/row keeps uint2 reads 8B-aligned
// for odd k.  LDS: 4 x 4608 = 18432 B/block.
// ---------------------------------------------------------------------------
__global__ __launch_bounds__(256, 4)
void edge_fused_kernel(const float* __restrict__ pos,
                       const int* __restrict__ batch,
                       const int* __restrict__ esrc,
                       const int* __restrict__ edst,
                       const float* __restrict__ shifts,
                       const float* __restrict__ cell,
                       const unsigned short* __restrict__ Wg,
                       const unsigned short* __restrict__ Bg,
                       const int* __restrict__ sortidx,
                       const float* __restrict__ Ai,
                       const int* __restrict__ hist,
                       float* __restrict__ out_g)
{
    __shared__ __align__(16) unsigned short actb[4][2304];   // 4 x 4608 B

    const int tid  = threadIdx.x;
    const int wave = tid >> 6;
    const int lane = tid & 63;
    const int q    = lane >> 4;
    const int n    = lane & 15;

    unsigned short* actw = actb[wave];

    // ---- geometry: lanes 0..31 own one edge each ----
    int   sd_self = 0;
    float uxr = 0.f, uyr = 0.f, uzr = 0.f;
    if (lane < 32) {
        int i = blockIdx.x * 128 + wave * 32 + lane;
        int e = sortidx[i];
        int s = esrc[e], d = edst[e];
        sd_self = s | (d << 16);
        int b = batch[s];
        const float* C = cell + b * 9;
        float sx = shifts[e * 3 + 0], sy = shifts[e * 3 + 1], sz = shifts[e * 3 + 2];
        float vx = pos[d * 3 + 0] - pos[s * 3 + 0] + sx * C[0] + sy * C[3] + sz * C[6];
        float vy = pos[d * 3 + 1] - pos[s * 3 + 1] + sx * C[1] + sy * C[4] + sz * C[7];
        float vz = pos[d * 3 + 2] - pos[s * 3 + 2] + sx * C[2] + sy * C[5] + sz * C[8];
        float len = sqrtf(vx * vx + vy * vy + vz * vz);
        float inv = 1.0f / fmaxf(len, 1e-9f);
        uxr = vx * inv; uyr = vy * inv; uzr = vz * inv;

        // soft_one_hot (sqrt(10) cancels with fc_W1's /sqrt(10))
        float embv[10];
        float base = len * 2.75f;
#pragma unroll
        for (int ii = 0; ii < 10; ++ii) {
            float ddv = base - (float)(ii + 1);
            embv[ii] = __expf(-ddv * ddv) * (1.0f / 1.12f);
        }
        unsigned int u0 = pk_bf16(embv[0], embv[1]);
        unsigned int u1 = pk_bf16(embv[2], embv[3]);
        unsigned int u2 = pk_bf16(embv[4], embv[5]);
        unsigned int u3 = pk_bf16(embv[6], embv[7]);
        unsigned int u4 = pk_bf16(embv[8], embv[9]);
        uint2* arow = (uint2*)&actw[lane * 72];   // cols 0..31 (K=32 padded)
        arow[0] = uint2{u0, u1};
        arow[1] = uint2{u2, u3};
        arow[2] = uint2{u4, 0u};
        arow[3] = uint2{0u, 0u};
        arow[4] = uint2{0u, 0u};
        arow[5] = uint2{0u, 0u};
        arow[6] = uint2{0u, 0u};
        arow[7] = uint2{0u, 0u};
    }
    // actw is per-wave, writers == readers wave: no barrier anywhere.

    union AF { unsigned int u[4]; short8 s8; };
    const f32x4 Z4 = (f32x4){0.f, 0.f, 0.f, 0.f};

    auto loadA = [&](int t, int kf) -> AF {
        const unsigned short* ap = &actw[(t * 16 + n) * 72 + kf * 32 + q * 8];
        uint2 a = *(const uint2*)ap;
        uint2 c = *(const uint2*)(ap + 4);
        AF f; f.u[0] = a.x; f.u[1] = a.y; f.u[2] = c.x; f.u[3] = c.y;
        return f;
    };
    auto loadW = [&](int f) -> short8 {   // direct global (L2-resident)
        return *(const short8*)&Wg[(f * 64 + lane) * 8];
    };

    // ---- layer 1: K=32 (padded emb), N=64, 2 edge-tiles ----
    {
        AF A1[2];
#pragma unroll
        for (int t = 0; t < 2; ++t) A1[t] = loadA(t, 0);
#pragma unroll
        for (int nt = 0; nt < 4; ++nt) {
            short8 W0 = loadW(nt);
            f32x4 Cc[2];
#pragma unroll
            for (int t = 0; t < 2; ++t)
                Cc[t] = __builtin_amdgcn_mfma_f32_16x16x32_bf16(A1[t].s8, W0, Z4, 0, 0, 0);
#pragma unroll
            for (int t = 0; t < 2; ++t)
#pragma unroll
                for (int r = 0; r < 4; ++r)
                    actw[(t * 16 + q * 4 + r) * 72 + nt * 16 + n] = f2bf(silu_f(Cc[t][r]));
        }
    }

    // ---- layer 2: K=64 ----
    {
        AF A2[2][2];
#pragma unroll
        for (int t = 0; t < 2; ++t)
#pragma unroll
            for (int kf = 0; kf < 2; ++kf) A2[t][kf] = loadA(t, kf);
#pragma unroll
        for (int nt = 0; nt < 4; ++nt) {
            short8 Wk0 = loadW(4 + nt);
            short8 Wk1 = loadW(8 + nt);
            f32x4 Cc[2];
#pragma unroll
            for (int t = 0; t < 2; ++t) {
                Cc[t] = __builtin_amdgcn_mfma_f32_16x16x32_bf16(A2[t][0].s8, Wk0, Z4, 0, 0, 0);
                Cc[t] = __builtin_amdgcn_mfma_f32_16x16x32_bf16(A2[t][1].s8, Wk1, Cc[t], 0, 0, 0);
            }
#pragma unroll
            for (int t = 0; t < 2; ++t)
#pragma unroll
                for (int r = 0; r < 4; ++r)
                    actw[(t * 16 + q * 4 + r) * 72 + nt * 16 + n] = f2bf(silu_f(Cc[t][r] * 0.125f));
        }
    }

    // ---- layer 3: K=64, epilogue -> w3 transposed [k][edge], stride 36 ----
    {
        AF A3[2][2];
#pragma unroll
        for (int t = 0; t < 2; ++t)
#pragma unroll
            for (int kf = 0; kf < 2; ++kf) A3[t][kf] = loadA(t, kf);
#pragma unroll
        for (int nt = 0; nt < 4; ++nt) {
            short8 Wk0 = loadW(12 + nt);
            short8 Wk1 = loadW(16 + nt);
            f32x4 Cc[2];
#pragma unroll
            for (int t = 0; t < 2; ++t) {
                Cc[t] = __builtin_amdgcn_mfma_f32_16x16x32_bf16(A3[t][0].s8, Wk0, Z4, 0, 0, 0);
                Cc[t] = __builtin_amdgcn_mfma_f32_16x16x32_bf16(A3[t][1].s8, Wk1, Cc[t], 0, 0, 0);
            }
#pragma unroll
            for (int t = 0; t < 2; ++t)
#pragma unroll
                for (int r = 0; r < 4; ++r)
                    actw[(nt * 16 + n) * 36 + t * 16 + q * 4 + r] = f2bf(silu_f(Cc[t][r] * 0.125f));
        }
    }

    // k-invariant P fragments: P[e, uv=h*32+q*8+j] = As[h*4+q]*Ad[j]
    AF P[2][2];
#pragma unroll
    for (int t = 0; t < 2; ++t) {
        int eL = t * 16 + n;                   // edge within wave [0,32)
        int sd = __shfl(sd_self, eL);
        int ss  = sd & 0xFFFF;
        int dd2 = sd >> 16;
        float As0 = Ai[ss * 8 + q];
        float As1 = Ai[ss * 8 + 4 + q];
        float4 d0 = *(const float4*)&Ai[dd2 * 8];
        float4 d1 = *(const float4*)&Ai[dd2 * 8 + 4];
        float Ad[8] = {d0.x, d0.y, d0.z, d0.w, d1.x, d1.y, d1.z, d1.w};
#pragma unroll
        for (int h = 0; h < 2; ++h) {
            float s0 = h ? As1 : As0;
            P[t][h].u[0] = pk_bf16(s0 * Ad[0], s0 * Ad[1]);
            P[t][h].u[1] = pk_bf16(s0 * Ad[2], s0 * Ad[3]);
            P[t][h].u[2] = pk_bf16(s0 * Ad[4], s0 * Ad[5]);
            P[t][h].u[3] = pk_bf16(s0 * Ad[6], s0 * Ad[7]);
        }
    }

    f32x4 out[2][2];
#pragma unroll
    for (int t = 0; t < 2; ++t)
#pragma unroll
        for (int nt = 0; nt < 2; ++nt)
            out[t][nt] = (f32x4){0.f, 0.f, 0.f, 0.f};

    // ---- B contraction: fragments straight from Bg (L2), no barriers ----
    const unsigned char* BgB = (const unsigned char*)Bg;
#pragma unroll 2
    for (int c = 0; c < 32; ++c) {
#pragma unroll
        for (int kk = 0; kk < 2; ++kk) {
            int k = c * 2 + kk;
            short8 Bf[2][2];
#pragma unroll
            for (int h = 0; h < 2; ++h)
#pragma unroll
                for (int nt = 0; nt < 2; ++nt)
                    Bf[h][nt] = *(const short8*)(BgB +
                        (((size_t)((c * 8 + kk * 4 + h * 2 + nt) * 64 + lane)) << 4));
#pragma unroll
            for (int t = 0; t < 2; ++t) {
                uint2 v = *(const uint2*)&actw[k * 36 + t * 16 + q * 4];
                float w0 = __uint_as_float(v.x << 16);
                float w1 = __uint_as_float(v.x & 0xFFFF0000u);
                float w2 = __uint_as_float(v.y << 16);
                float w3 = __uint_as_float(v.y & 0xFFFF0000u);
#pragma unroll
                for (int nt = 0; nt < 2; ++nt) {
                    f32x4 Q = __builtin_amdgcn_mfma_f32_16x16x32_bf16(
                        P[t][0].s8, Bf[0][nt], Z4, 0, 0, 0);
                    Q = __builtin_amdgcn_mfma_f32_16x16x32_bf16(
                        P[t][1].s8, Bf[1][nt], Q, 0, 0, 0);
                    out[t][nt][0] += w0 * Q[0];
                    out[t][nt][1] += w1 * Q[1];
                    out[t][nt][2] += w2 * Q[2];
                    out[t][nt][3] += w3 * Q[3];
                }
            }
        }
    }

    // ---- epilogue: feat rows -> LDS (stride 33), per-wave segmented
    // reduction; sd/u pulled via __shfl from the edge-owning lanes ----
    float* featL = (float*)actw;   // [32][33] fp32 = 4224 B (buffer 4608)
#pragma unroll
    for (int t = 0; t < 2; ++t) {
#pragma unroll
        for (int r = 0; r < 4; ++r) {
            int row = t * 16 + q * 4 + r;
            featL[row * 33 + n]      = out[t][0][r];
            featL[row * 33 + 16 + n] = out[t][1][r];
        }
    }
    // same-wave ds write->read: lockstep + compiler lgkmcnt, no barrier

    {
        const float s3c  = 1.7320508075688772f;
        const float s5c  = 2.2360679774997896f;
        const float s15c = 3.872983346207417f;
        int j = lane;
        int cc = 0, mode = 0, m = 0;
        if (j < 16)      { cc = j; mode = 0; }
        else if (j < 40) { int w = (j - 16) / 3; m = (j - 16) % 3; cc = 16 + w; mode = 1; }
        else if (j < 60) { int w = (j - 40) / 5; m = (j - 40) % 5; cc = 24 + w; mode = 2; }
        // lanes 60..63: dummy (cc=0, mode=0), no atomics

        int cur_d = __shfl(sd_self, 0) >> 16;
        float acc = 0.f;
        for (int e2 = 0; e2 < 32; ++e2) {
            int   sdv = __shfl(sd_self, e2);
            float uxe = __shfl(uxr, e2);
            float uye = __shfl(uyr, e2);
            float uze = __shfl(uzr, e2);
            int d_e = sdv >> 16;                 // wave-uniform
            if (d_e != cur_d) {
                if (j < 60) {
                    int cnt = hist[cur_d];
                    atomicAdd(&out_g[cur_d * 60 + j], acc * (1.0f / 64.0f) / (float)cnt);
                }
                acc = 0.f;
                cur_d = d_e;
            }
            float f = featL[e2 * 33 + cc];
            float sh = 1.f;
            if (mode == 1) {
                sh = s3c * (m == 0 ? uxe : (m == 1 ? uye : uze));
            } else if (mode == 2) {
                if (m == 0)      sh = s15c * uxe * uze;
                else if (m == 1) sh = s15c * uxe * uye;
                else if (m == 2) sh = s5c * (uye * uye - 0.5f * (uxe * uxe + uze * uze));
                else if (m == 3) sh = s15c * uye * uze;
                else             sh = 0.5f * s15c * (uze * uze - uxe * uxe);
            }
            acc += f * sh;
        }
        if (j < 60) {
            int cnt = hist[cur_d];
            atomicAdd(&out_g[cur_d * 60 + j], acc * (1.0f / 64.0f) / (float)cnt);
        }
    }
}

extern "C" void kernel_launch(void* const* d_in, const int* in_sizes, int n_in,
                              void* d_out, int out_size, void* d_ws, size_t ws_size,
                              hipStream_t stream)
{
    const float* pos     = (const float*)d_in[0];
    const int*   A       = (const int*)d_in[1];
    const int*   batch   = (const int*)d_in[2];
    const int*   esrc    = (const int*)d_in[3];
    const int*   edst    = (const int*)d_in[4];
    const float* shifts  = (const float*)d_in[5];
    const float* cell    = (const float*)d_in[6];
    const float* emb_tab = (const float*)d_in[7];
    const float* fitW1   = (const float*)d_in[8];
    const float* fitb1   = (const float*)d_in[9];
    const float* fitW2   = (const float*)d_in[10];
    const float* fitb2   = (const float*)d_in[11];
    const float* fitW3   = (const float*)d_in[12];
    const float* fitb3   = (const float*)d_in[13];
    const float* fcW1    = (const float*)d_in[14];
    const float* fcW2    = (const float*)d_in[15];
    const float* fcW3    = (const float*)d_in[16];
    const float* fcW4    = (const float*)d_in[17];

    float* out = (float*)d_out;

    // workspace layout (all 16B-aligned)
    char* W = (char*)d_ws;
    float* Ai      = (float*)W;  W += (size_t)NN * 8 * 4;        // 320000
    int* sortidx   = (int*)W;    W += (size_t)NE * 4;            // 524288
    int* rank      = (int*)W;    W += (size_t)NE * 4;            // 524288
    int* hist      = (int*)W;    W += (size_t)NN * 4;            // 40000
    unsigned short* Bg = (unsigned short*)W; W += (size_t)131072 * 2;
    unsigned short* Wg = (unsigned short*)W; W += (size_t)10240 * 2;

    // D0: zero hist only (rank is fully overwritten by prep)
    hipMemsetAsync(hist, 0, (size_t)NN * 4, stream);

    // D1: prep (MLP, W/B fragment packing, histogram + rank, out zeroing)
    prep_kernel<<<692, 256, 0, stream>>>(
        A, edst, emb_tab, fitW1, fitb1, fitW2, fitb2, fitW3, fitb3,
        fcW1, fcW2, fcW3, fcW4, hist, rank, out, Ai, Wg, Bg);

    // D2: per-block redundant scan + atomic-free scatter
    scanrank_kernel<<<NE / 256, 256, 0, stream>>>(edst, hist, rank, sortidx);

    // D3: fused edge pipeline (32 edges/wave, 1024 blocks, barrier-free)
    edge_fused_kernel<<<NE / 128, 256, 0, stream>>>(
        pos, batch, esrc, edst, shifts, cell, Wg, Bg,
        sortidx, Ai, hist, out);
}

// Round 10
// 187.202 us; speedup vs baseline: 1.1414x; 1.1414x over previous
//
#include <hip/hip_runtime.h>
#include <hip/hip_bf16.h>
#include <math.h>

#define NN 10000
#define NE 131072

typedef __attribute__((ext_vector_type(8))) short short8;
typedef __attribute__((ext_vector_type(4))) float f32x4;

__device__ __forceinline__ float silu_f(float x) {
    return x / (1.0f + __expf(-x));
}

// round-to-nearest-even f32 -> bf16 (finite inputs only)
__device__ __forceinline__ unsigned short f2bf(float f) {
    unsigned int u = __float_as_uint(f);
    u += 0x7FFFu + ((u >> 16) & 1u);
    return (unsigned short)(u >> 16);
}

// packed pair via HW v_cvt_pk_bf16_f32 (x = low half)
__device__ __forceinline__ unsigned int pk_bf16(float lo, float hi) {
    __hip_bfloat162 h = __float22bfloat162_rn(float2{lo, hi});
    return *reinterpret_cast<unsigned int*>(&h);
}

// ---------------------------------------------------------------------------
// D1: prep (692 blocks).  hist already zeroed by D0 memset.  (R7-proven)
// ---------------------------------------------------------------------------
__global__ __launch_bounds__(256)
void prep_kernel(const int* __restrict__ A,
                 const int* __restrict__ edst,
                 const float* __restrict__ emb_tab,
                 const float* __restrict__ W1, const float* __restrict__ b1,
                 const float* __restrict__ W2, const float* __restrict__ b2,
                 const float* __restrict__ W3, const float* __restrict__ b3,
                 const float* __restrict__ fcW1,
                 const float* __restrict__ fcW2,
                 const float* __restrict__ fcW3,
                 const float* __restrict__ fcW4,
                 int* __restrict__ hist,
                 int* __restrict__ rank,
                 float* __restrict__ outg,
                 float* __restrict__ Ai,
                 unsigned short* __restrict__ Wg,
                 unsigned short* __restrict__ Bg)
{
    const int blk = blockIdx.x;
    const int tid = threadIdx.x;

    if (blk < 40) {
        // node MLP -> Ai
        int nd = blk * 256 + tid;
        if (nd >= NN) return;
        int a = A[nd];
        float h[16];
#pragma unroll
        for (int i = 0; i < 16; ++i) h[i] = emb_tab[a * 16 + i];
        float h1[64];
#pragma unroll
        for (int j = 0; j < 64; ++j) h1[j] = b1[j];
#pragma unroll
        for (int i = 0; i < 16; ++i) {
            float hv = h[i];
#pragma unroll
            for (int j = 0; j < 64; ++j) h1[j] += hv * W1[i * 64 + j];
        }
#pragma unroll
        for (int j = 0; j < 64; ++j) h1[j] = silu_f(h1[j]);
        float h2[32];
#pragma unroll
        for (int j = 0; j < 32; ++j) h2[j] = b2[j];
#pragma unroll
        for (int i = 0; i < 64; ++i) {
            float hv = h1[i];
#pragma unroll
            for (int j = 0; j < 32; ++j) h2[j] += hv * W2[i * 32 + j];
        }
#pragma unroll
        for (int j = 0; j < 32; ++j) h2[j] = silu_f(h2[j]);
#pragma unroll
        for (int j = 0; j < 8; ++j) {
            float s = b3[j];
#pragma unroll
            for (int i = 0; i < 32; ++i) s += h2[i] * W3[i * 8 + j];
            Ai[nd * 8 + j] = s;
        }
    } else if (blk < 80) {
        // prep_W: 20 frags of 512 bf16
        int i = (blk - 40) * 256 + tid;   // [0, 10240)
        int j    = i & 7;
        int lane = (i >> 3) & 63;
        int f    = i >> 9;
        int q = lane >> 4, n = lane & 15;
        int L, kf, nt;
        if (f < 4)       { L = 1; kf = 0;             nt = f; }
        else if (f < 12) { L = 2; kf = (f - 4) >> 2;  nt = (f - 4) & 3; }
        else             { L = 3; kf = (f - 12) >> 2; nt = (f - 12) & 3; }
        int k = kf * 32 + q * 8 + j;
        int col = nt * 16 + n;
        float v = 0.0f;
        if (L == 1)      { if (k < 10) v = fcW1[k * 64 + col]; }
        else if (L == 2) v = fcW2[k * 64 + col];
        else             v = fcW3[k * 64 + col];
        Wg[i] = f2bf(v);
    } else if (blk < 592) {
        // prep_B inverse-mapped + histogram/rank
        int linear = (blk - 80) * 256 + tid;   // [0, 131072)
        rank[linear] = atomicAdd(&hist[edst[linear]], 1);
        if (linear < 114688) {                 // 64 * 1792 real elements
            int k = linear / 1792;
            int t = linear - k * 1792;
            int uv, wc;
            if (t < 1024)      { uv = t >> 4;            wc = t & 15; }
            else if (t < 1536) { int r = t - 1024; uv = r >> 3; wc = 16 + (r & 7); }
            else               { int r = t - 1536; uv = r >> 2; wc = 24 + (r & 3); }
            int h  = uv >> 5;
            int q  = (uv >> 3) & 3;
            int j  = uv & 7;
            int nt = wc >> 4;
            int n  = wc & 15;
            int i  = (k << 11) | (h << 10) | (nt << 9) | (((q << 4) | n) << 3) | j;
            Bg[i] = f2bf(fcW4[linear]);
        } else {                               // zero padding: wc in [28,32)
            int z  = linear - 114688;          // [0, 16384)
            int k  = z >> 8;
            int r  = z & 255;
            int uv = r >> 2;
            int c2 = z & 3;
            int h  = uv >> 5;
            int q  = (uv >> 3) & 3;
            int j  = uv & 7;
            int i  = (k << 11) | (h << 10) | (1 << 9) | (((q << 4) | (12 + c2)) << 3) | j;
            Bg[i] = 0;
        }
    } else {
        // zero out
        int t = (blk - 592) * 256 + tid;
        float4 z = float4{0.f, 0.f, 0.f, 0.f};
        for (int r = t; r < 150000; r += 25600)
            ((float4*)outg)[r] = z;
    }
}

// ---------------------------------------------------------------------------
// D2: scan+scatter (512 blocks), atomic-free.  (R7-proven)
// ---------------------------------------------------------------------------
__global__ __launch_bounds__(256)
void scanrank_kernel(const int* __restrict__ edst,
                     const int* __restrict__ hist,
                     const int* __restrict__ rank,
                     int* __restrict__ sortidx)
{
    __shared__ int offs[NN];    // 40000 B
    __shared__ int part[256];
    const int tid = threadIdx.x;

    int loc[40];
    int s = 0;
    if (tid < 250) {
        const int4* h4 = (const int4*)(hist) + tid * 10;
#pragma unroll
        for (int v = 0; v < 10; ++v) {
            int4 x = h4[v];
            loc[v * 4 + 0] = x.x; loc[v * 4 + 1] = x.y;
            loc[v * 4 + 2] = x.z; loc[v * 4 + 3] = x.w;
            s += x.x + x.y + x.z + x.w;
        }
    } else {
#pragma unroll
        for (int r = 0; r < 40; ++r) loc[r] = 0;
    }
    part[tid] = s;
    __syncthreads();
#pragma unroll
    for (int off = 1; off < 256; off <<= 1) {
        int v = (tid >= off) ? part[tid - off] : 0;
        __syncthreads();
        part[tid] += v;
        __syncthreads();
    }
    if (tid < 250) {
        int run = part[tid] - s;
        int base = tid * 40;
#pragma unroll
        for (int r = 0; r < 40; ++r) { offs[base + r] = run; run += loc[r]; }
    }
    __syncthreads();

    int e = blockIdx.x * 256 + tid;
    int d = edst[e];
    sortidx[offs[d] + rank[e]] = e;
}

// ---------------------------------------------------------------------------
// D3: fused edge pipeline (R8 structure: 64 edges/wave, 512 blocks,
// de-staged, ZERO barriers) + EXPLICIT REGISTER DOUBLE-BUFFER for the B
// fragment stream.  R8's regression vs R7 was exposed L2 latency on the
// 4 dependent 16B loads per k-pair at only 2 waves/SIMD; BA/BB (2x8 short8
// = 64 VGPR) prefetch chunk c+1 while chunk c computes (~350cy compute >>
// ~200cy L2 latency -> hidden).  All buffer indexing is static (rule #20).
// LDS: actb 34816 + sdb 1024 + shb 8192 = 44032 B.
// ---------------------------------------------------------------------------
__global__ __launch_bounds__(256, 2)
void edge_fused_kernel(const float* __restrict__ pos,
                       const int* __restrict__ batch,
                       const int* __restrict__ esrc,
                       const int* __restrict__ edst,
                       const float* __restrict__ shifts,
                       const float* __restrict__ cell,
                       const unsigned short* __restrict__ Wg,
                       const unsigned short* __restrict__ Bg,
                       const int* __restrict__ sortidx,
                       const float* __restrict__ Ai,
                       const int* __restrict__ hist,
                       float* __restrict__ out_g)
{
    __shared__ __align__(16) unsigned short actb[4][64 * 68]; // 4 x 8.5 KB
    __shared__ int   sdb[256];                                // packed s | (d<<16)
    __shared__ __align__(16) float shb[4][64 * 8];            // per-edge sh table

    const int tid  = threadIdx.x;
    const int wave = tid >> 6;
    const int lane = tid & 63;
    const int q    = lane >> 4;
    const int n    = lane & 15;
    const int i    = blockIdx.x * 256 + wave * 64 + lane;

    unsigned short* actw = actb[wave];

    // ---- geometry (1 lane = 1 edge) ----
    int e = sortidx[i];
    int s = esrc[e], d = edst[e];
    sdb[wave * 64 + lane] = s | (d << 16);
    int b = batch[s];
    const float* C = cell + b * 9;
    float sx = shifts[e * 3 + 0], sy = shifts[e * 3 + 1], sz = shifts[e * 3 + 2];
    float vx = pos[d * 3 + 0] - pos[s * 3 + 0] + sx * C[0] + sy * C[3] + sz * C[6];
    float vy = pos[d * 3 + 1] - pos[s * 3 + 1] + sx * C[1] + sy * C[4] + sz * C[7];
    float vz = pos[d * 3 + 2] - pos[s * 3 + 2] + sx * C[2] + sy * C[5] + sz * C[8];
    float len = sqrtf(vx * vx + vy * vy + vz * vz);
    float inv = 1.0f / fmaxf(len, 1e-9f);
    float ux = vx * inv, uy = vy * inv, uz = vz * inv;
    {
        const float s3c  = 1.7320508075688772f;
        const float s5c  = 2.2360679774997896f;
        const float s15c = 3.872983346207417f;
        float* shw = shb[wave];
        *(float4*)&shw[lane * 8]     = float4{s3c * ux, s3c * uy, s3c * uz,
                                              s15c * ux * uz};
        *(float4*)&shw[lane * 8 + 4] = float4{s15c * ux * uy,
                                              s5c * (uy * uy - 0.5f * (ux * ux + uz * uz)),
                                              s15c * uy * uz,
                                              0.5f * s15c * (uz * uz - ux * ux)};
    }

    // soft_one_hot (sqrt(10) cancels with fc_W1's /sqrt(10))
    float embv[10];
    float base = len * 2.75f;
#pragma unroll
    for (int ii = 0; ii < 10; ++ii) {
        float ddv = base - (float)(ii + 1);
        embv[ii] = __expf(-ddv * ddv) * (1.0f / 1.12f);
    }
    {
        unsigned int u0 = pk_bf16(embv[0], embv[1]);
        unsigned int u1 = pk_bf16(embv[2], embv[3]);
        unsigned int u2 = pk_bf16(embv[4], embv[5]);
        unsigned int u3 = pk_bf16(embv[6], embv[7]);
        unsigned int u4 = pk_bf16(embv[8], embv[9]);
        uint2* arow = (uint2*)&actw[lane * 68];
        arow[0] = uint2{u0, u1};
        arow[1] = uint2{u2, u3};
        arow[2] = uint2{u4, 0u};
        arow[3] = uint2{0u, 0u};
        arow[4] = uint2{0u, 0u};
        arow[5] = uint2{0u, 0u};
        arow[6] = uint2{0u, 0u};
        arow[7] = uint2{0u, 0u};
    }
    // all LDS from here on is per-wave: no barrier needed anywhere.

    union AF { unsigned int u[4]; short8 s8; };
    const f32x4 Z4 = (f32x4){0.f, 0.f, 0.f, 0.f};

    auto loadA = [&](int t, int kf) -> AF {
        const unsigned short* ap = &actw[(t * 16 + n) * 68 + kf * 32 + q * 8];
        uint2 a = *(const uint2*)ap;
        uint2 c = *(const uint2*)(ap + 4);
        AF f; f.u[0] = a.x; f.u[1] = a.y; f.u[2] = c.x; f.u[3] = c.y;
        return f;
    };
    auto loadW = [&](int f) -> short8 {   // direct global (L2-resident)
        return *(const short8*)&Wg[(f * 64 + lane) * 8];
    };

    // ---- layer 1: K=32 (padded emb), N=64 ----
    {
        AF A1[4];
#pragma unroll
        for (int t = 0; t < 4; ++t) A1[t] = loadA(t, 0);
#pragma unroll
        for (int nt = 0; nt < 4; ++nt) {
            short8 W0 = loadW(nt);
            f32x4 Cc[4];
#pragma unroll
            for (int t = 0; t < 4; ++t)
                Cc[t] = __builtin_amdgcn_mfma_f32_16x16x32_bf16(A1[t].s8, W0, Z4, 0, 0, 0);
#pragma unroll
            for (int t = 0; t < 4; ++t)
#pragma unroll
                for (int r = 0; r < 4; ++r)
                    actw[(t * 16 + q * 4 + r) * 68 + nt * 16 + n] = f2bf(silu_f(Cc[t][r]));
        }
    }

    // ---- layer 2: K=64 ----
    {
        AF A2[4][2];
#pragma unroll
        for (int t = 0; t < 4; ++t)
#pragma unroll
            for (int kf = 0; kf < 2; ++kf) A2[t][kf] = loadA(t, kf);
#pragma unroll
        for (int nt = 0; nt < 4; ++nt) {
            short8 Wk0 = loadW(4 + nt);
            short8 Wk1 = loadW(8 + nt);
            f32x4 Cc[4];
#pragma unroll
            for (int t = 0; t < 4; ++t) {
                Cc[t] = __builtin_amdgcn_mfma_f32_16x16x32_bf16(A2[t][0].s8, Wk0, Z4, 0, 0, 0);
                Cc[t] = __builtin_amdgcn_mfma_f32_16x16x32_bf16(A2[t][1].s8, Wk1, Cc[t], 0, 0, 0);
            }
#pragma unroll
            for (int t = 0; t < 4; ++t)
#pragma unroll
                for (int r = 0; r < 4; ++r)
                    actw[(t * 16 + q * 4 + r) * 68 + nt * 16 + n] = f2bf(silu_f(Cc[t][r] * 0.125f));
        }
    }

    // ---- layer 3: K=64, epilogue -> w3 transposed [k][edge] in actw ----
    {
        AF A3[4][2];
#pragma unroll
        for (int t = 0; t < 4; ++t)
#pragma unroll
            for (int kf = 0; kf < 2; ++kf) A3[t][kf] = loadA(t, kf);
#pragma unroll
        for (int nt = 0; nt < 4; ++nt) {
            short8 Wk0 = loadW(12 + nt);
            short8 Wk1 = loadW(16 + nt);
            f32x4 Cc[4];
#pragma unroll
            for (int t = 0; t < 4; ++t) {
                Cc[t] = __builtin_amdgcn_mfma_f32_16x16x32_bf16(A3[t][0].s8, Wk0, Z4, 0, 0, 0);
                Cc[t] = __builtin_amdgcn_mfma_f32_16x16x32_bf16(A3[t][1].s8, Wk1, Cc[t], 0, 0, 0);
            }
#pragma unroll
            for (int t = 0; t < 4; ++t)
#pragma unroll
                for (int r = 0; r < 4; ++r)
                    actw[(nt * 16 + n) * 68 + t * 16 + q * 4 + r] = f2bf(silu_f(Cc[t][r] * 0.125f));
        }
    }

    // ---- register double-buffered B stream ----
    const unsigned char* BgB = (const unsigned char*)Bg;
    short8 BA[8], BB[8];

    auto LOADB = [&](short8 (&Bf)[8], int c) {
#pragma unroll
        for (int f = 0; f < 8; ++f)
            Bf[f] = *(const short8*)(BgB +
                (((size_t)((c * 8 + f) * 64 + lane)) << 4));
    };

    LOADB(BA, 0);   // issue chunk-0 loads; latency hides under P-pack below

    // k-invariant P fragments: P[e, uv=h*32+q*8+j] = As[h*4+q]*Ad[j]
    AF P[4][2];
#pragma unroll
    for (int t = 0; t < 4; ++t) {
        int eL = wave * 64 + t * 16 + n;
        int sd = sdb[eL];
        int ss  = sd & 0xFFFF;
        int dd2 = sd >> 16;
        float As0 = Ai[ss * 8 + q];
        float As1 = Ai[ss * 8 + 4 + q];
        float4 d0 = *(const float4*)&Ai[dd2 * 8];
        float4 d1 = *(const float4*)&Ai[dd2 * 8 + 4];
        float Ad[8] = {d0.x, d0.y, d0.z, d0.w, d1.x, d1.y, d1.z, d1.w};
#pragma unroll
        for (int h = 0; h < 2; ++h) {
            float s0 = h ? As1 : As0;
            P[t][h].u[0] = pk_bf16(s0 * Ad[0], s0 * Ad[1]);
            P[t][h].u[1] = pk_bf16(s0 * Ad[2], s0 * Ad[3]);
            P[t][h].u[2] = pk_bf16(s0 * Ad[4], s0 * Ad[5]);
            P[t][h].u[3] = pk_bf16(s0 * Ad[6], s0 * Ad[7]);
        }
    }

    f32x4 out[4][2];
#pragma unroll
    for (int t = 0; t < 4; ++t)
#pragma unroll
        for (int nt = 0; nt < 2; ++nt)
            out[t][nt] = (f32x4){0.f, 0.f, 0.f, 0.f};

    // fragment index f = kk*4 + h*2 + nt  (matches Bg layout)
    auto COMPUTE = [&](short8 (&Bf)[8], int c) {
#pragma unroll
        for (int kk = 0; kk < 2; ++kk) {
            int k = c * 2 + kk;
#pragma unroll
            for (int t = 0; t < 4; ++t) {
                uint2 v = *(const uint2*)&actw[k * 68 + t * 16 + q * 4];
                float w0 = __uint_as_float(v.x << 16);
                float w1 = __uint_as_float(v.x & 0xFFFF0000u);
                float w2 = __uint_as_float(v.y << 16);
                float w3 = __uint_as_float(v.y & 0xFFFF0000u);
#pragma unroll
                for (int nt = 0; nt < 2; ++nt) {
                    f32x4 Q = __builtin_amdgcn_mfma_f32_16x16x32_bf16(
                        P[t][0].s8, Bf[kk * 4 + nt], Z4, 0, 0, 0);
                    Q = __builtin_amdgcn_mfma_f32_16x16x32_bf16(
                        P[t][1].s8, Bf[kk * 4 + 2 + nt], Q, 0, 0, 0);
                    out[t][nt][0] += w0 * Q[0];
                    out[t][nt][1] += w1 * Q[1];
                    out[t][nt][2] += w2 * Q[2];
                    out[t][nt][3] += w3 * Q[3];
                }
            }
        }
    };

#pragma unroll 1
    for (int cp = 0; cp < 16; ++cp) {
        int c0 = cp * 2, c1 = c0 + 1;
        LOADB(BB, c1);                 // prefetch odd chunk
        COMPUTE(BA, c0);               // ~350cy: hides BB's latency
        if (cp < 15) LOADB(BA, c0 + 2);// prefetch next even chunk
        COMPUTE(BB, c1);               // hides BA's latency
    }

    // ---- epilogue: feat rows -> LDS (stride 33), per-wave segmented
    // reduction using the precomputed sh table ----
    float* featL = (float*)actw;   // [64][33] fp32 = 8448 B
#pragma unroll
    for (int t = 0; t < 4; ++t) {
#pragma unroll
        for (int r = 0; r < 4; ++r) {
            int row = t * 16 + q * 4 + r;
            featL[row * 33 + n]      = out[t][0][r];
            featL[row * 33 + 16 + n] = out[t][1][r];
        }
    }
    // same-wave ds write->read: lockstep + compiler lgkmcnt, no barrier needed

    if (lane < 60) {
        int j = lane;
        int cc, sidx = 0;
        bool is0 = (j < 16);
        if (j < 16)      { cc = j; }
        else if (j < 40) { cc = 16 + (j - 16) / 3; sidx = (j - 16) % 3; }
        else             { cc = 24 + (j - 40) / 5; sidx = 3 + (j - 40) % 5; }

        const float* shw = shb[wave];
        int cur_d = sdb[wave * 64] >> 16;
        float acc = 0.f;
        for (int e2 = 0; e2 < 64; ++e2) {
            int d_e = sdb[wave * 64 + e2] >> 16;   // wave-uniform
            if (d_e != cur_d) {
                int cnt = hist[cur_d];
                atomicAdd(&out_g[cur_d * 60 + j], acc * (1.0f / 64.0f) / (float)cnt);
                acc = 0.f;
                cur_d = d_e;
            }
            float f  = featL[e2 * 33 + cc];
            float sh = shw[e2 * 8 + sidx];
            if (is0) sh = 1.0f;
            acc += f * sh;
        }
        int cnt = hist[cur_d];
        atomicAdd(&out_g[cur_d * 60 + j], acc * (1.0f / 64.0f) / (float)cnt);
    }
}

extern "C" void kernel_launch(void* const* d_in, const int* in_sizes, int n_in,
                              void* d_out, int out_size, void* d_ws, size_t ws_size,
                              hipStream_t stream)
{
    const float* pos     = (const float*)d_in[0];
    const int*   A       = (const int*)d_in[1];
    const int*   batch   = (const int*)d_in[2];
    const int*   esrc    = (const int*)d_in[3];
    const int*   edst    = (const int*)d_in[4];
    const float* shifts  = (const float*)d_in[5];
    const float* cell    = (const float*)d_in[6];
    const float* emb_tab = (const float*)d_in[7];
    const float* fitW1   = (const float*)d_in[8];
    const float* fitb1   = (const float*)d_in[9];
    const float* fitW2   = (const float*)d_in[10];
    const float* fitb2   = (const float*)d_in[11];
    const float* fitW3   = (const float*)d_in[12];
    const float* fitb3   = (const float*)d_in[13];
    const float* fcW1    = (const float*)d_in[14];
    const float* fcW2    = (const float*)d_in[15];
    const float* fcW3    = (const float*)d_in[16];
    const float* fcW4    = (const float*)d_in[17];

    float* out = (float*)d_out;

    // workspace layout (all 16B-aligned)
    char* W = (char*)d_ws;
    float* Ai      = (float*)W;  W += (size_t)NN * 8 * 4;        // 320000
    int* sortidx   = (int*)W;    W += (size_t)NE * 4;            // 524288
    int* rank      = (int*)W;    W += (size_t)NE * 4;            // 524288
    int* hist      = (int*)W;    W += (size_t)NN * 4;            // 40000
    unsigned short* Bg = (unsigned short*)W; W += (size_t)131072 * 2;
    unsigned short* Wg = (unsigned short*)W; W += (size_t)10240 * 2;

    // D0: zero hist only (rank is fully overwritten by prep)
    hipMemsetAsync(hist, 0, (size_t)NN * 4, stream);

    // D1: prep (MLP, W/B fragment packing, histogram + rank, out zeroing)
    prep_kernel<<<692, 256, 0, stream>>>(
        A, edst, emb_tab, fitW1, fitb1, fitW2, fitb2, fitW3, fitb3,
        fcW1, fcW2, fcW3, fcW4, hist, rank, out, Ai, Wg, Bg);

    // D2: per-block redundant scan + atomic-free scatter
    scanrank_kernel<<<NE / 256, 256, 0, stream>>>(edst, hist, rank, sortidx);

    // D3: fused edge pipeline (reg-dbuf B prefetch, barrier-free)
    edge_fused_kernel<<<NE / 256, 256, 0, stream>>>(
        pos, batch, esrc, edst, shifts, cell, Wg, Bg,
        sortidx, Ai, hist, out);
}